// Round 1
// baseline (1056.760 us; speedup 1.0000x reference)
//
#include <hip/hip_runtime.h>
#include <cstdint>

// Problem constants: L=S=1024, N=4, E=1024, H=16, D=64
// ws layout (float offsets):
static const size_t OFF_QW2 = 0;              // [k*64+i][j]  1,048,576
static const size_t OFF_QB2 = 1048576;        // [k*64+i]     1,024
static const size_t OFF_QW  = 1049600;        // [n][k][l][i] 4,194,304
static const size_t OFF_KH  = OFF_QW + 4194304;
static const size_t OFF_VH  = OFF_KH + 4194304;
static const size_t OFF_ST  = OFF_VH + 4194304; // [n][k][l][{m,Z}] 131,072
static const size_t OFF_O   = OFF_ST + 131072;  // [l][n][e]    4,194,304

// ---------------------------------------------------------------------------
// K0: fold attn_W into q_w:  qw2[(k,i),j] = sum_o q_w[o*16+k, j]*attn_W[o,i,k]/32
//     qbias2[(k,i)] = sum_o in_bias[0][o*16+k]*attn_W[o,i,k]/32
__global__ __launch_bounds__(256) void k_qw2(const float* __restrict__ qw,
    const float* __restrict__ attnW, const float* __restrict__ bias0,
    float* __restrict__ qw2, float* __restrict__ qb2) {
  const int b = blockIdx.x;          // = k*64 + i
  const int k = b >> 6, i = b & 63;
  const int tid = threadIdx.x;
  __shared__ float aw[64];
  if (tid < 64) aw[tid] = attnW[(tid * 64 + i) * 16 + k] * 0.03125f; // fold 1/sqrt(E)
  __syncthreads();
  for (int j = tid; j < 1024; j += 256) {
    float acc = 0.f;
#pragma unroll 8
    for (int o = 0; o < 64; ++o) acc = fmaf(qw[(o * 16 + k) * 1024 + j], aw[o], acc);
    qw2[(size_t)b * 1024 + j] = acc;
  }
  if (tid == 0) {
    float acc = 0.f;
    for (int o = 0; o < 64; ++o) acc = fmaf(bias0[o * 16 + k], aw[o], acc);
    qb2[b] = acc;
  }
}

// ---------------------------------------------------------------------------
// Generic fp32 GEMM: C[m,o] = sum_j A[m,j]*B(o,j) + bias[o]
// M=4096, N=1024, K=1024. BM=BN=128, BK=16, 256 thr, 8x8/thread.
// MODE 0: B=qw2 rows [o=k*64+i][j]; epilogue -> Qw[n][k][l][i]
// MODE 1: B=k_w/v_w rows [o=i*16+k][j]; epilogue -> Kh/Vh[n][k][s][i]
// MODE 2: B=out_w [j][o]; epilogue -> direct C[m*1024+o]
template <int MODE>
__global__ __launch_bounds__(256) void k_gemm(const float* __restrict__ A,
    const float* __restrict__ B, const float* __restrict__ bias, float* __restrict__ C) {
  __shared__ float As[16][128];
  __shared__ float Bs[16][132];
  const int tid = threadIdx.x;
  const int tx = tid & 15, ty = tid >> 4;
  const int m0 = blockIdx.y * 128, o0 = blockIdx.x * 128;
  float acc[8][8];
#pragma unroll
  for (int r = 0; r < 8; ++r)
#pragma unroll
    for (int c = 0; c < 8; ++c) acc[r][c] = 0.f;

  for (int j0 = 0; j0 < 1024; j0 += 16) {
#pragma unroll
    for (int q = 0; q < 2; ++q) {
      const int idx = tid * 2 + q;
      const int row = idx >> 2, jc = (idx & 3) << 2;
      const float4 v = *(const float4*)(A + (size_t)(m0 + row) * 1024 + j0 + jc);
      As[jc + 0][row] = v.x; As[jc + 1][row] = v.y;
      As[jc + 2][row] = v.z; As[jc + 3][row] = v.w;
    }
    if (MODE == 2) {
#pragma unroll
      for (int q = 0; q < 2; ++q) {
        const int idx = tid * 2 + q;
        const int jj = idx >> 5, oc = (idx & 31) << 2;
        const float4 v = *(const float4*)(B + (size_t)(j0 + jj) * 1024 + o0 + oc);
        *(float4*)&Bs[jj][oc] = v;
      }
    } else {
#pragma unroll
      for (int q = 0; q < 2; ++q) {
        const int idx = tid * 2 + q;
        const int orow = idx >> 2, jc = (idx & 3) << 2;
        const float4 v = *(const float4*)(B + (size_t)(o0 + orow) * 1024 + j0 + jc);
        Bs[jc + 0][orow] = v.x; Bs[jc + 1][orow] = v.y;
        Bs[jc + 2][orow] = v.z; Bs[jc + 3][orow] = v.w;
      }
    }
    __syncthreads();
#pragma unroll
    for (int j = 0; j < 16; ++j) {
      float a[8], bb[8];
      *(float4*)&a[0]  = *(const float4*)&As[j][ty * 8];
      *(float4*)&a[4]  = *(const float4*)&As[j][ty * 8 + 4];
      *(float4*)&bb[0] = *(const float4*)&Bs[j][tx * 8];
      *(float4*)&bb[4] = *(const float4*)&Bs[j][tx * 8 + 4];
#pragma unroll
      for (int r = 0; r < 8; ++r)
#pragma unroll
        for (int c = 0; c < 8; ++c) acc[r][c] = fmaf(a[r], bb[c], acc[r][c]);
    }
    __syncthreads();
  }
#pragma unroll
  for (int r = 0; r < 8; ++r) {
    const int m = m0 + ty * 8 + r;
#pragma unroll
    for (int c = 0; c < 8; ++c) {
      const int o = o0 + tx * 8 + c;
      const float v = acc[r][c] + bias[o];
      if (MODE == 0) {
        const int kk = o >> 6, ii = o & 63, l = m >> 2, n = m & 3;
        C[(((size_t)(n * 16 + kk) * 1024 + l) << 6) + ii] = v;
      } else if (MODE == 1) {
        const int kk = o & 15, ii = o >> 4, s = m >> 2, n = m & 3;
        C[(((size_t)(n * 16 + kk) * 1024 + s) << 6) + ii] = v;
      } else {
        C[(size_t)m * 1024 + o] = v;
      }
    }
  }
}

// ---------------------------------------------------------------------------
// Flash pass 1: per (n,k,l-tile=64) compute online-softmax stats m,Z over all S.
// 4 waves; wave w covers s-cols w*16.. per 64-s tile; lane=(pr,qc): rows pr*4+r,
// s-cols w*16+qc*4+c. LDS holds Q,K transposed [i][row] so fragment reads are
// single b128 per 4 rows/cols (conflict-free).
__global__ __launch_bounds__(256) void k_pass1(const float* __restrict__ Qw,
    const float* __restrict__ Kh, float* __restrict__ stats) {
  __shared__ float Qts[64][68];
  __shared__ float Kts[64][68];
  __shared__ float red[4][64][2];
  const int b = blockIdx.x;
  const int lt = b & 15, k = (b >> 4) & 15, n = b >> 8;
  const int l0 = lt * 64;
  const int tid = threadIdx.x, w = tid >> 6, lane = tid & 63;
  const int pr = lane >> 2, qc = lane & 3;
  const float* Qbase = Qw + ((size_t)(n * 16 + k) * 1024 + l0) * 64;
  const float* Kbase = Kh + (size_t)(n * 16 + k) * 1024 * 64;
#pragma unroll
  for (int q = 0; q < 4; ++q) {
    const int idx = tid + q * 256;
    const int row = idx >> 4, ic = (idx & 15) << 2;
    const float4 v = *(const float4*)(Qbase + row * 64 + ic);
    Qts[ic + 0][row] = v.x; Qts[ic + 1][row] = v.y;
    Qts[ic + 2][row] = v.z; Qts[ic + 3][row] = v.w;
  }
  float m[4], Z[4];
#pragma unroll
  for (int r = 0; r < 4; ++r) { m[r] = -1e30f; Z[r] = 0.f; }
  for (int s0 = 0; s0 < 1024; s0 += 64) {
    __syncthreads();
#pragma unroll
    for (int q = 0; q < 4; ++q) {
      const int idx = tid + q * 256;
      const int row = idx >> 4, ic = (idx & 15) << 2;
      const float4 v = *(const float4*)(Kbase + (size_t)(s0 + row) * 64 + ic);
      Kts[ic + 0][row] = v.x; Kts[ic + 1][row] = v.y;
      Kts[ic + 2][row] = v.z; Kts[ic + 3][row] = v.w;
    }
    __syncthreads();
    float acc[4][4];
#pragma unroll
    for (int r = 0; r < 4; ++r)
#pragma unroll
      for (int c = 0; c < 4; ++c) acc[r][c] = 0.f;
#pragma unroll 4
    for (int i = 0; i < 64; ++i) {
      float qa[4], kb[4];
      *(float4*)qa = *(const float4*)&Qts[i][pr * 4];
      *(float4*)kb = *(const float4*)&Kts[i][w * 16 + qc * 4];
#pragma unroll
      for (int r = 0; r < 4; ++r)
#pragma unroll
        for (int c = 0; c < 4; ++c) acc[r][c] = fmaf(qa[r], kb[c], acc[r][c]);
    }
#pragma unroll
    for (int r = 0; r < 4; ++r) {
      float tm = fmaxf(fmaxf(acc[r][0], acc[r][1]), fmaxf(acc[r][2], acc[r][3]));
      tm = fmaxf(tm, __shfl_xor(tm, 1));
      tm = fmaxf(tm, __shfl_xor(tm, 2));
      const float nm = fmaxf(m[r], tm);
      float es = __expf(acc[r][0] - nm) + __expf(acc[r][1] - nm) +
                 __expf(acc[r][2] - nm) + __expf(acc[r][3] - nm);
      es += __shfl_xor(es, 1);
      es += __shfl_xor(es, 2);
      Z[r] = Z[r] * __expf(m[r] - nm) + es;
      m[r] = nm;
    }
  }
  if (qc == 0) {
#pragma unroll
    for (int r = 0; r < 4; ++r) {
      red[w][pr * 4 + r][0] = m[r];
      red[w][pr * 4 + r][1] = Z[r];
    }
  }
  __syncthreads();
  if (tid < 64) {
    float mm = red[0][tid][0];
    for (int ww = 1; ww < 4; ++ww) mm = fmaxf(mm, red[ww][tid][0]);
    float zz = 0.f;
    for (int ww = 0; ww < 4; ++ww) zz += red[ww][tid][1] * __expf(red[ww][tid][0] - mm);
    const size_t o = ((size_t)(n * 16 + k) * 1024 + l0 + tid) * 2;
    stats[o] = mm;
    stats[o + 1] = zz;
  }
}

// ---------------------------------------------------------------------------
// Flash pass 2a: per (n,k,l-tile=64): recompute scores, normalize with final
// (m,Z), PV-accumulate O. p tile goes through LDS (aliased onto the K buffer)
// to re-map from the QK lane layout to the PV lane layout.
__global__ __launch_bounds__(256) void k_pass2a(const float* __restrict__ Qw,
    const float* __restrict__ Kh, const float* __restrict__ Vh,
    const float* __restrict__ stats, float* __restrict__ O) {
  __shared__ float Qts[64][68];
  __shared__ float KP[64][68];   // Kts during QK; pT[s][r] after mid-barrier
  __shared__ float Vs[64][64];
  const int b = blockIdx.x;
  const int lt = b & 15, k = (b >> 4) & 15, n = b >> 8;
  const int l0 = lt * 64;
  const int tid = threadIdx.x, w = tid >> 6, lane = tid & 63;
  const int pr = lane >> 2, qc = lane & 3;
  const int tr = tid >> 4, ti = tid & 15;     // PV mapping: rows tr*4.., i-cols ti*4..
  const float* Qbase = Qw + ((size_t)(n * 16 + k) * 1024 + l0) * 64;
  const float* Kbase = Kh + (size_t)(n * 16 + k) * 1024 * 64;
  const float* Vbase = Vh + (size_t)(n * 16 + k) * 1024 * 64;
#pragma unroll
  for (int q = 0; q < 4; ++q) {
    const int idx = tid + q * 256;
    const int row = idx >> 4, ic = (idx & 15) << 2;
    const float4 v = *(const float4*)(Qbase + row * 64 + ic);
    Qts[ic + 0][row] = v.x; Qts[ic + 1][row] = v.y;
    Qts[ic + 2][row] = v.z; Qts[ic + 3][row] = v.w;
  }
  float mr[4], iz[4];
#pragma unroll
  for (int r = 0; r < 4; ++r) {
    const float2 mz = *(const float2*)(stats + ((size_t)(n * 16 + k) * 1024 + l0 + pr * 4 + r) * 2);
    mr[r] = mz.x;
    iz[r] = 1.f / mz.y;
  }
  float oacc[4][4];
#pragma unroll
  for (int r = 0; r < 4; ++r)
#pragma unroll
    for (int c = 0; c < 4; ++c) oacc[r][c] = 0.f;

  for (int s0 = 0; s0 < 1024; s0 += 64) {
    __syncthreads();                       // prev PV done before restaging
#pragma unroll
    for (int q = 0; q < 4; ++q) {
      const int idx = tid + q * 256;
      const int row = idx >> 4, ic = (idx & 15) << 2;
      const float4 v = *(const float4*)(Kbase + (size_t)(s0 + row) * 64 + ic);
      KP[ic + 0][row] = v.x; KP[ic + 1][row] = v.y;
      KP[ic + 2][row] = v.z; KP[ic + 3][row] = v.w;
      const float4 vv = *(const float4*)(Vbase + (size_t)(s0 + row) * 64 + ic);
      *(float4*)&Vs[row][ic] = vv;
    }
    __syncthreads();
    float acc[4][4];
#pragma unroll
    for (int r = 0; r < 4; ++r)
#pragma unroll
      for (int c = 0; c < 4; ++c) acc[r][c] = 0.f;
#pragma unroll 4
    for (int i = 0; i < 64; ++i) {
      float qa[4], kb[4];
      *(float4*)qa = *(const float4*)&Qts[i][pr * 4];
      *(float4*)kb = *(const float4*)&KP[i][w * 16 + qc * 4];
#pragma unroll
      for (int r = 0; r < 4; ++r)
#pragma unroll
        for (int c = 0; c < 4; ++c) acc[r][c] = fmaf(qa[r], kb[c], acc[r][c]);
    }
    __syncthreads();                       // all K reads done; reuse KP as pT
#pragma unroll
    for (int r = 0; r < 4; ++r)
#pragma unroll
      for (int c = 0; c < 4; ++c)
        KP[w * 16 + qc * 4 + c][pr * 4 + r] = __expf(acc[r][c] - mr[r]) * iz[r];
    __syncthreads();                       // pT visible
#pragma unroll 4
    for (int s = 0; s < 64; ++s) {
      float pv[4], vv[4];
      *(float4*)pv = *(const float4*)&KP[s][tr * 4];
      *(float4*)vv = *(const float4*)&Vs[s][ti * 4];
#pragma unroll
      for (int r = 0; r < 4; ++r)
#pragma unroll
        for (int c = 0; c < 4; ++c) oacc[r][c] = fmaf(pv[r], vv[c], oacc[r][c]);
    }
  }
#pragma unroll
  for (int r = 0; r < 4; ++r) {
    const int l = l0 + tr * 4 + r;
#pragma unroll
    for (int c = 0; c < 4; ++c) {
      const int i = ti * 4 + c;
      O[(size_t)(l * 4 + n) * 1024 + i * 16 + k] = oacc[r][c];  // e = i*16 + k
    }
  }
}

// ---------------------------------------------------------------------------
// Flash pass 2b: per (n, l-tile=64, s-tile=64): recompute scores for all 16
// heads, sum normalized probs -> Wmap[l][s][n] (flat (l,s,n) order, /H).
__global__ __launch_bounds__(256) void k_pass2b(const float* __restrict__ Qw,
    const float* __restrict__ Kh, const float* __restrict__ stats,
    float* __restrict__ Wmap) {
  __shared__ float Qts[64][68];
  __shared__ float Kts[64][68];
  const int b = blockIdx.x;
  const int st = b & 15, lt = (b >> 4) & 15, n = b >> 8;
  const int l0 = lt * 64, s0 = st * 64;
  const int tid = threadIdx.x, w = tid >> 6, lane = tid & 63;
  const int pr = lane >> 2, qc = lane & 3;
  float wsum[4][4];
#pragma unroll
  for (int r = 0; r < 4; ++r)
#pragma unroll
    for (int c = 0; c < 4; ++c) wsum[r][c] = 0.f;

  for (int k = 0; k < 16; ++k) {
    const float* Qbase = Qw + ((size_t)(n * 16 + k) * 1024 + l0) * 64;
    const float* Kbase = Kh + ((size_t)(n * 16 + k) * 1024 + s0) * 64;
    __syncthreads();
#pragma unroll
    for (int q = 0; q < 4; ++q) {
      const int idx = tid + q * 256;
      const int row = idx >> 4, ic = (idx & 15) << 2;
      const float4 v = *(const float4*)(Qbase + row * 64 + ic);
      Qts[ic + 0][row] = v.x; Qts[ic + 1][row] = v.y;
      Qts[ic + 2][row] = v.z; Qts[ic + 3][row] = v.w;
      const float4 vk = *(const float4*)(Kbase + row * 64 + ic);
      Kts[ic + 0][row] = vk.x; Kts[ic + 1][row] = vk.y;
      Kts[ic + 2][row] = vk.z; Kts[ic + 3][row] = vk.w;
    }
    __syncthreads();
    float acc[4][4];
#pragma unroll
    for (int r = 0; r < 4; ++r)
#pragma unroll
      for (int c = 0; c < 4; ++c) acc[r][c] = 0.f;
#pragma unroll 4
    for (int i = 0; i < 64; ++i) {
      float qa[4], kb[4];
      *(float4*)qa = *(const float4*)&Qts[i][pr * 4];
      *(float4*)kb = *(const float4*)&Kts[i][w * 16 + qc * 4];
#pragma unroll
      for (int r = 0; r < 4; ++r)
#pragma unroll
        for (int c = 0; c < 4; ++c) acc[r][c] = fmaf(qa[r], kb[c], acc[r][c]);
    }
#pragma unroll
    for (int r = 0; r < 4; ++r) {
      const float2 mz = *(const float2*)(stats + ((size_t)(n * 16 + k) * 1024 + l0 + pr * 4 + r) * 2);
      const float izr = 1.f / mz.y;
#pragma unroll
      for (int c = 0; c < 4; ++c)
        wsum[r][c] = fmaf(__expf(acc[r][c] - mz.x), izr, wsum[r][c]);
    }
  }
#pragma unroll
  for (int r = 0; r < 4; ++r) {
    const int l = l0 + pr * 4 + r;
#pragma unroll
    for (int c = 0; c < 4; ++c) {
      const int s = s0 + w * 16 + qc * 4 + c;
      Wmap[((size_t)l * 1024 + s) * 4 + n] = wsum[r][c] * 0.0625f;  // /H
    }
  }
}

// ---------------------------------------------------------------------------
extern "C" void kernel_launch(void* const* d_in, const int* in_sizes, int n_in,
                              void* d_out, int out_size, void* d_ws, size_t ws_size,
                              hipStream_t stream) {
  (void)in_sizes; (void)n_in; (void)out_size; (void)ws_size;
  const float* Q        = (const float*)d_in[0];
  const float* K        = (const float*)d_in[1];
  const float* V        = (const float*)d_in[2];
  const float* q_w      = (const float*)d_in[3];
  const float* k_w      = (const float*)d_in[4];
  const float* v_w      = (const float*)d_in[5];
  const float* out_w    = (const float*)d_in[6];
  const float* in_bias  = (const float*)d_in[7];
  const float* out_bias = (const float*)d_in[8];
  const float* attn_W   = (const float*)d_in[9];
  float* ws  = (float*)d_ws;
  float* qw2 = ws + OFF_QW2;
  float* qb2 = ws + OFF_QB2;
  float* Qw  = ws + OFF_QW;
  float* Kh  = ws + OFF_KH;
  float* Vh  = ws + OFF_VH;
  float* st  = ws + OFF_ST;
  float* O   = ws + OFF_O;
  float* out  = (float*)d_out;
  float* Wmap = out + 4194304;

  k_qw2<<<1024, 256, 0, stream>>>(q_w, attn_W, in_bias, qw2, qb2);
  k_gemm<0><<<dim3(8, 32), 256, 0, stream>>>(Q, qw2, qb2, Qw);
  k_gemm<1><<<dim3(8, 32), 256, 0, stream>>>(K, k_w, in_bias + 1024, Kh);
  k_gemm<1><<<dim3(8, 32), 256, 0, stream>>>(V, v_w, in_bias + 2048, Vh);
  k_pass1<<<1024, 256, 0, stream>>>(Qw, Kh, st);
  k_pass2a<<<1024, 256, 0, stream>>>(Qw, Kh, Vh, st, O);
  k_pass2b<<<1024, 256, 0, stream>>>(Qw, Kh, st, Wmap);
  k_gemm<2><<<dim3(8, 32), 256, 0, stream>>>(O, out_w, out_bias, out);
}

// Round 2
// 636.853 us; speedup vs baseline: 1.6593x; 1.6593x over previous
//
#include <hip/hip_runtime.h>
#include <cstdint>

// Problem constants: L=S=1024, N=4, E=1024, H=16, D=64
typedef __bf16 bf16x8 __attribute__((ext_vector_type(8)));
typedef float f32x4 __attribute__((ext_vector_type(4)));

// ws layout (float-unit offsets):
static const size_t OFF_QW2BF = 0;                    // [k*64+i][j] bf16 (1M ushort)
static const size_t OFF_KWBF  = 524288;               // [o][j] bf16
static const size_t OFF_VWBF  = 1048576;              // [o][j] bf16
static const size_t OFF_OWTBF = 1572864;              // [o][j] bf16 (out_w^T)
static const size_t OFF_QB2   = 2097152;              // 1024 f32
static const size_t OFF_QW    = 2098176;              // [n][k][l][i] f32 4M
static const size_t OFF_KH    = OFF_QW + 4194304;
static const size_t OFF_VH    = OFF_KH + 4194304;
static const size_t OFF_ST    = OFF_VH + 4194304;     // [n][k][l][{m,Z}] 131072
static const size_t OFF_OBF   = OFF_ST + 131072;      // [l*4+n][e] bf16 (4M ushort)

__device__ inline unsigned short f2bf(float f) {
  union { float f; unsigned u; } v; v.f = f;
  const unsigned r = v.u + 0x7FFFu + ((v.u >> 16) & 1u);   // RNE
  return (unsigned short)(r >> 16);
}

// ---------------------------------------------------------------------------
// K0: fold attn_W into q_w (bf16 out): qw2[(k,i),j] = sum_o q_w[o*16+k,j]*attn_W[o,i,k]/32
__global__ __launch_bounds__(256) void k_qw2(const float* __restrict__ qw,
    const float* __restrict__ attnW, const float* __restrict__ bias0,
    unsigned short* __restrict__ qw2, float* __restrict__ qb2) {
  const int b = blockIdx.x;          // = k*64 + i
  const int k = b >> 6, i = b & 63;
  const int tid = threadIdx.x;
  __shared__ float aw[64];
  if (tid < 64) aw[tid] = attnW[(tid * 64 + i) * 16 + k] * 0.03125f; // fold 1/sqrt(E)
  __syncthreads();
  for (int j = tid; j < 1024; j += 256) {
    float acc = 0.f;
#pragma unroll 8
    for (int o = 0; o < 64; ++o) acc = fmaf(qw[(o * 16 + k) * 1024 + j], aw[o], acc);
    qw2[(size_t)b * 1024 + j] = f2bf(acc);
  }
  if (tid == 0) {
    float acc = 0.f;
    for (int o = 0; o < 64; ++o) acc = fmaf(bias0[o * 16 + k], aw[o], acc);
    qb2[b] = acc;
  }
}

// ---------------------------------------------------------------------------
// Convert k_w and v_w to bf16 (row layout preserved: [o][j])
__global__ __launch_bounds__(256) void k_cvt2(const float* __restrict__ a,
    const float* __restrict__ b, unsigned short* __restrict__ oa,
    unsigned short* __restrict__ ob) {
  const int i = blockIdx.x * 256 + threadIdx.x;   // 262144 float4 per matrix
  const float4 va = ((const float4*)a)[i];
  ushort4 ha; ha.x = f2bf(va.x); ha.y = f2bf(va.y); ha.z = f2bf(va.z); ha.w = f2bf(va.w);
  ((ushort4*)oa)[i] = ha;
  const float4 vb = ((const float4*)b)[i];
  ushort4 hb; hb.x = f2bf(vb.x); hb.y = f2bf(vb.y); hb.z = f2bf(vb.z); hb.w = f2bf(vb.w);
  ((ushort4*)ob)[i] = hb;
}

// ---------------------------------------------------------------------------
// Transpose out_w [j][o] -> owT [o][j] bf16
__global__ __launch_bounds__(256) void k_tr(const float* __restrict__ w,
    unsigned short* __restrict__ wt) {
  __shared__ float t[64][65];
  const int j0 = blockIdx.y * 64, o0 = blockIdx.x * 64;
  const int tid = threadIdx.x;
  const int r = tid >> 4, c4 = tid & 15;
#pragma unroll
  for (int q = 0; q < 4; ++q) {
    const int row = r + q * 16;
    const float4 v = *(const float4*)&w[(size_t)(j0 + row) * 1024 + o0 + c4 * 4];
    t[row][c4 * 4 + 0] = v.x; t[row][c4 * 4 + 1] = v.y;
    t[row][c4 * 4 + 2] = v.z; t[row][c4 * 4 + 3] = v.w;
  }
  __syncthreads();
#pragma unroll
  for (int q = 0; q < 4; ++q) {
    const int orow = r + q * 16;
    ushort4 h;
    h.x = f2bf(t[c4 * 4 + 0][orow]); h.y = f2bf(t[c4 * 4 + 1][orow]);
    h.z = f2bf(t[c4 * 4 + 2][orow]); h.w = f2bf(t[c4 * 4 + 3][orow]);
    *(ushort4*)&wt[(size_t)(o0 + orow) * 1024 + j0 + c4 * 4] = h;
  }
}

// ---------------------------------------------------------------------------
// bf16 MFMA GEMM: C[m,o] = sum_j A[m,j]*B[o,j] + bias[o].  M=4096,O=1024,K=1024.
// 128x128 tile, BK=32, 256 thr = 4 waves (2x2 of 64x64), mfma 16x16x32.
// MODE 0: A fp32 (Q), epilogue scatter -> Qw[n][k][l][i] (o = k*64+i)
// MODE 1: A fp32 (K/V), epilogue scatter -> Kh/Vh[n][k][s][i] (o = i*16+k)
// MODE 2: A bf16 (Obf), epilogue direct C[m*1024+o]
template <int MODE>
__global__ __launch_bounds__(256) void k_gemm(const void* __restrict__ Ap,
    const unsigned short* __restrict__ Bbf, const float* __restrict__ bias,
    float* __restrict__ C) {
  __shared__ unsigned short As[128][40];   // [m][k] pad 8 -> 80B rows, conflict-light
  __shared__ unsigned short Bs[128][40];   // [o][k]
  const int tid = threadIdx.x;
  const int wid = tid >> 6, lane = tid & 63;
  const int wr = wid >> 1, wc = wid & 1;
  const int lr = lane & 15, lk = lane >> 4;
  const int m0 = blockIdx.y * 128, o0 = blockIdx.x * 128;
  f32x4 acc[4][4];
#pragma unroll
  for (int i = 0; i < 4; ++i)
#pragma unroll
    for (int j = 0; j < 4; ++j) acc[i][j] = (f32x4){0.f, 0.f, 0.f, 0.f};

  for (int k0 = 0; k0 < 1024; k0 += 32) {
    if (MODE == 2) {
      const unsigned short* A = (const unsigned short*)Ap;
#pragma unroll
      for (int q = 0; q < 2; ++q) {
        const int idx = tid + q * 256;
        const int row = idx >> 2, c8 = idx & 3;
        *(int4*)&As[row][c8 * 8] =
            *(const int4*)&A[(size_t)(m0 + row) * 1024 + k0 + c8 * 8];
      }
    } else {
      const float* A = (const float*)Ap;
#pragma unroll
      for (int q = 0; q < 4; ++q) {
        const int idx = tid + q * 256;
        const int row = idx >> 3, c4 = idx & 7;
        const float4 v = *(const float4*)&A[(size_t)(m0 + row) * 1024 + k0 + c4 * 4];
        ushort4 h; h.x = f2bf(v.x); h.y = f2bf(v.y); h.z = f2bf(v.z); h.w = f2bf(v.w);
        *(ushort4*)&As[row][c4 * 4] = h;
      }
    }
#pragma unroll
    for (int q = 0; q < 2; ++q) {
      const int idx = tid + q * 256;
      const int row = idx >> 2, c8 = idx & 3;
      *(int4*)&Bs[row][c8 * 8] =
          *(const int4*)&Bbf[(size_t)(o0 + row) * 1024 + k0 + c8 * 8];
    }
    __syncthreads();
    bf16x8 af[4], bfr[4];
#pragma unroll
    for (int f = 0; f < 4; ++f)
      af[f] = *(const bf16x8*)&As[wr * 64 + f * 16 + lr][lk * 8];
#pragma unroll
    for (int f = 0; f < 4; ++f)
      bfr[f] = *(const bf16x8*)&Bs[wc * 64 + f * 16 + lr][lk * 8];
#pragma unroll
    for (int i = 0; i < 4; ++i)
#pragma unroll
      for (int j = 0; j < 4; ++j)
        acc[i][j] = __builtin_amdgcn_mfma_f32_16x16x32_bf16(af[i], bfr[j], acc[i][j], 0, 0, 0);
    __syncthreads();
  }
  // epilogue: lane holds C col = lane&15, rows (lane>>4)*4 + t  [verified m89/m91]
#pragma unroll
  for (int fi = 0; fi < 4; ++fi)
#pragma unroll
    for (int fj = 0; fj < 4; ++fj) {
      const int o = o0 + wc * 64 + fj * 16 + lr;
      const float bo = bias[o];
#pragma unroll
      for (int t = 0; t < 4; ++t) {
        const int m = m0 + wr * 64 + fi * 16 + lk * 4 + t;
        const float v = acc[fi][fj][t] + bo;
        if (MODE == 0) {
          const int kk = o >> 6, ii = o & 63, l = m >> 2, n = m & 3;
          C[(((size_t)(n * 16 + kk) * 1024 + l) << 6) + ii] = v;
        } else if (MODE == 1) {
          const int kk = o & 15, ii = o >> 4, s = m >> 2, n = m & 3;
          C[(((size_t)(n * 16 + kk) * 1024 + s) << 6) + ii] = v;
        } else {
          C[(size_t)m * 1024 + o] = v;
        }
      }
    }
}

// ---------------------------------------------------------------------------
// Fused flash pass (replaces pass1+pass2a): per (n,k,l-tile=64), online softmax
// with O-rescale; writes final stats (m,Z) for pass2b and O in bf16 [l*4+n][i*16+k].
// Per-row (m,Z) owned by thread tid<64 (tid==row); scratch via LDS pads.
__global__ __launch_bounds__(256) void k_flash(const float* __restrict__ Qw,
    const float* __restrict__ Kh, const float* __restrict__ Vh,
    float* __restrict__ stats, unsigned short* __restrict__ Obf) {
  __shared__ float Qts[64][68];   // Q^T; pad cols [64..67]: wave-max, then fac/invz
  __shared__ float KP[64][68];    // K^T during QK; pT[s][r] after; pad: wave-sums
  __shared__ float Vs[64][64];
  __shared__ float mrow[64];
  const int b = blockIdx.x;
  const int lt = b & 15, k = (b >> 4) & 15, n = b >> 8;
  const int l0 = lt * 64;
  const int tid = threadIdx.x, w = tid >> 6, lane = tid & 63;
  const int pr = lane >> 2, qc = lane & 3;
  const int tr = tid >> 4, ti = tid & 15;     // PV mapping
  const float* Qbase = Qw + ((size_t)(n * 16 + k) * 1024 + l0) * 64;
  const float* Kbase = Kh + (size_t)(n * 16 + k) * 1024 * 64;
  const float* Vbase = Vh + (size_t)(n * 16 + k) * 1024 * 64;
#pragma unroll
  for (int q = 0; q < 4; ++q) {
    const int idx = tid + q * 256;
    const int row = idx >> 4, ic = (idx & 15) << 2;
    const float4 v = *(const float4*)(Qbase + row * 64 + ic);
    Qts[ic + 0][row] = v.x; Qts[ic + 1][row] = v.y;
    Qts[ic + 2][row] = v.z; Qts[ic + 3][row] = v.w;
  }
  if (tid < 64) mrow[tid] = -1e30f;
  float om = -1e30f, oz = 0.f;     // row-owner state (tid<64)
  float oacc[4][4];
#pragma unroll
  for (int r = 0; r < 4; ++r)
#pragma unroll
    for (int c = 0; c < 4; ++c) oacc[r][c] = 0.f;

  for (int s0 = 0; s0 < 1024; s0 += 64) {
    __syncthreads();                       // B0: prev PV + fac reads done
#pragma unroll
    for (int q = 0; q < 4; ++q) {
      const int idx = tid + q * 256;
      const int row = idx >> 4, ic = (idx & 15) << 2;
      const float4 v = *(const float4*)(Kbase + (size_t)(s0 + row) * 64 + ic);
      KP[ic + 0][row] = v.x; KP[ic + 1][row] = v.y;
      KP[ic + 2][row] = v.z; KP[ic + 3][row] = v.w;
      const float4 vv = *(const float4*)(Vbase + (size_t)(s0 + row) * 64 + ic);
      *(float4*)&Vs[row][ic] = vv;
    }
    __syncthreads();                       // B1: K/V staged
    float acc[4][4];
#pragma unroll
    for (int r = 0; r < 4; ++r)
#pragma unroll
      for (int c = 0; c < 4; ++c) acc[r][c] = 0.f;
#pragma unroll 4
    for (int i = 0; i < 64; ++i) {
      float qa[4], kb[4];
      *(float4*)qa = *(const float4*)&Qts[i][pr * 4];
      *(float4*)kb = *(const float4*)&KP[i][w * 16 + qc * 4];
#pragma unroll
      for (int r = 0; r < 4; ++r)
#pragma unroll
        for (int c = 0; c < 4; ++c) acc[r][c] = fmaf(qa[r], kb[c], acc[r][c]);
    }
    // wave-local row max -> pad
#pragma unroll
    for (int r = 0; r < 4; ++r) {
      float tm = fmaxf(fmaxf(acc[r][0], acc[r][1]), fmaxf(acc[r][2], acc[r][3]));
      tm = fmaxf(tm, __shfl_xor(tm, 1));
      tm = fmaxf(tm, __shfl_xor(tm, 2));
      if (qc == 0) Qts[pr * 4 + r][64 + w] = tm;
    }
    __syncthreads();                       // B2: wave maxes visible; K reads done
#pragma unroll
    for (int r = 0; r < 4; ++r) {
      const int row = pr * 4 + r;
      const float mn = fmaxf(fmaxf(fmaxf(Qts[row][64], Qts[row][65]),
                                   fmaxf(Qts[row][66], Qts[row][67])), mrow[row]);
      float ps = 0.f;
#pragma unroll
      for (int c = 0; c < 4; ++c) {
        const float p = __expf(acc[r][c] - mn);
        KP[w * 16 + qc * 4 + c][row] = p;   // pT (unnormalized)
        ps += p;
      }
      ps += __shfl_xor(ps, 1);
      ps += __shfl_xor(ps, 2);
      if (qc == 0) KP[row][64 + w] = ps;    // wave row-sum -> pad
    }
    __syncthreads();                       // B3: pT + sums visible
    if (tid < 64) {
      const float mn = fmaxf(fmaxf(fmaxf(Qts[tid][64], Qts[tid][65]),
                                   fmaxf(Qts[tid][66], Qts[tid][67])), om);
      const float f = __expf(om - mn);
      oz = oz * f + (KP[tid][64] + KP[tid][65] + KP[tid][66] + KP[tid][67]);
      om = mn;
      mrow[tid] = mn;
      Qts[tid][64] = f;                     // rescale factor for PV lanes
    }
    __syncthreads();                       // B4: fac visible
#pragma unroll
    for (int r = 0; r < 4; ++r) {
      const float f = Qts[tr * 4 + r][64];
#pragma unroll
      for (int c = 0; c < 4; ++c) oacc[r][c] *= f;
    }
#pragma unroll 4
    for (int s = 0; s < 64; ++s) {
      float pv[4], vv[4];
      *(float4*)pv = *(const float4*)&KP[s][tr * 4];
      *(float4*)vv = *(const float4*)&Vs[s][ti * 4];
#pragma unroll
      for (int r = 0; r < 4; ++r)
#pragma unroll
        for (int c = 0; c < 4; ++c) oacc[r][c] = fmaf(pv[r], vv[c], oacc[r][c]);
    }
  }
  __syncthreads();                         // last PV fac reads done
  if (tid < 64) {
    const size_t so = ((size_t)(n * 16 + k) * 1024 + l0 + tid) * 2;
    stats[so] = om;
    stats[so + 1] = oz;
    Qts[tid][64] = 1.f / oz;
  }
  __syncthreads();
#pragma unroll
  for (int r = 0; r < 4; ++r) {
    const int l = l0 + tr * 4 + r;
    const float iz = Qts[tr * 4 + r][64];
#pragma unroll
    for (int c = 0; c < 4; ++c) {
      const int i = ti * 4 + c;
      Obf[(size_t)(l * 4 + n) * 1024 + i * 16 + k] = f2bf(oacc[r][c] * iz);
    }
  }
}

// ---------------------------------------------------------------------------
// Flash pass 2b: per (n, l-tile=64, s-tile=64): recompute scores for all 16
// heads, sum normalized probs -> Wmap[l][s][n] (flat (l,s,n) order, /H).
__global__ __launch_bounds__(256) void k_pass2b(const float* __restrict__ Qw,
    const float* __restrict__ Kh, const float* __restrict__ stats,
    float* __restrict__ Wmap) {
  __shared__ float Qts[64][68];
  __shared__ float Kts[64][68];
  const int b = blockIdx.x;
  const int st = b & 15, lt = (b >> 4) & 15, n = b >> 8;
  const int l0 = lt * 64, s0 = st * 64;
  const int tid = threadIdx.x, w = tid >> 6, lane = tid & 63;
  const int pr = lane >> 2, qc = lane & 3;
  float wsum[4][4];
#pragma unroll
  for (int r = 0; r < 4; ++r)
#pragma unroll
    for (int c = 0; c < 4; ++c) wsum[r][c] = 0.f;

  for (int k = 0; k < 16; ++k) {
    const float* Qbase = Qw + ((size_t)(n * 16 + k) * 1024 + l0) * 64;
    const float* Kbase = Kh + ((size_t)(n * 16 + k) * 1024 + s0) * 64;
    __syncthreads();
#pragma unroll
    for (int q = 0; q < 4; ++q) {
      const int idx = tid + q * 256;
      const int row = idx >> 4, ic = (idx & 15) << 2;
      const float4 v = *(const float4*)(Qbase + row * 64 + ic);
      Qts[ic + 0][row] = v.x; Qts[ic + 1][row] = v.y;
      Qts[ic + 2][row] = v.z; Qts[ic + 3][row] = v.w;
      const float4 vk = *(const float4*)(Kbase + row * 64 + ic);
      Kts[ic + 0][row] = vk.x; Kts[ic + 1][row] = vk.y;
      Kts[ic + 2][row] = vk.z; Kts[ic + 3][row] = vk.w;
    }
    __syncthreads();
    float acc[4][4];
#pragma unroll
    for (int r = 0; r < 4; ++r)
#pragma unroll
      for (int c = 0; c < 4; ++c) acc[r][c] = 0.f;
#pragma unroll 4
    for (int i = 0; i < 64; ++i) {
      float qa[4], kb[4];
      *(float4*)qa = *(const float4*)&Qts[i][pr * 4];
      *(float4*)kb = *(const float4*)&Kts[i][w * 16 + qc * 4];
#pragma unroll
      for (int r = 0; r < 4; ++r)
#pragma unroll
        for (int c = 0; c < 4; ++c) acc[r][c] = fmaf(qa[r], kb[c], acc[r][c]);
    }
#pragma unroll
    for (int r = 0; r < 4; ++r) {
      const float2 mz = *(const float2*)(stats + ((size_t)(n * 16 + k) * 1024 + l0 + pr * 4 + r) * 2);
      const float izr = 1.f / mz.y;
#pragma unroll
      for (int c = 0; c < 4; ++c)
        wsum[r][c] = fmaf(__expf(acc[r][c] - mz.x), izr, wsum[r][c]);
    }
  }
#pragma unroll
  for (int r = 0; r < 4; ++r) {
    const int l = l0 + pr * 4 + r;
#pragma unroll
    for (int c = 0; c < 4; ++c) {
      const int s = s0 + w * 16 + qc * 4 + c;
      Wmap[((size_t)l * 1024 + s) * 4 + n] = wsum[r][c] * 0.0625f;  // /H
    }
  }
}

// ---------------------------------------------------------------------------
extern "C" void kernel_launch(void* const* d_in, const int* in_sizes, int n_in,
                              void* d_out, int out_size, void* d_ws, size_t ws_size,
                              hipStream_t stream) {
  (void)in_sizes; (void)n_in; (void)out_size; (void)ws_size;
  const float* Q        = (const float*)d_in[0];
  const float* K        = (const float*)d_in[1];
  const float* V        = (const float*)d_in[2];
  const float* q_w      = (const float*)d_in[3];
  const float* k_w      = (const float*)d_in[4];
  const float* v_w      = (const float*)d_in[5];
  const float* out_w    = (const float*)d_in[6];
  const float* in_bias  = (const float*)d_in[7];
  const float* out_bias = (const float*)d_in[8];
  const float* attn_W   = (const float*)d_in[9];
  float* ws = (float*)d_ws;
  unsigned short* qw2bf = (unsigned short*)(ws + OFF_QW2BF);
  unsigned short* kwbf  = (unsigned short*)(ws + OFF_KWBF);
  unsigned short* vwbf  = (unsigned short*)(ws + OFF_VWBF);
  unsigned short* owtbf = (unsigned short*)(ws + OFF_OWTBF);
  float* qb2 = ws + OFF_QB2;
  float* Qw  = ws + OFF_QW;
  float* Kh  = ws + OFF_KH;
  float* Vh  = ws + OFF_VH;
  float* st  = ws + OFF_ST;
  unsigned short* Obf = (unsigned short*)(ws + OFF_OBF);
  float* out  = (float*)d_out;
  float* Wmap = out + 4194304;

  k_qw2<<<1024, 256, 0, stream>>>(q_w, attn_W, in_bias, qw2bf, qb2);
  k_cvt2<<<1024, 256, 0, stream>>>(k_w, v_w, kwbf, vwbf);
  k_tr<<<dim3(16, 16), 256, 0, stream>>>(out_w, owtbf);
  k_gemm<0><<<dim3(8, 32), 256, 0, stream>>>(Q, qw2bf, qb2, Qw);
  k_gemm<1><<<dim3(8, 32), 256, 0, stream>>>(K, kwbf, in_bias + 1024, Kh);
  k_gemm<1><<<dim3(8, 32), 256, 0, stream>>>(V, vwbf, in_bias + 2048, Vh);
  k_flash<<<1024, 256, 0, stream>>>(Qw, Kh, Vh, st, Obf);
  k_pass2b<<<1024, 256, 0, stream>>>(Qw, Kh, st, Wmap);
  k_gemm<2><<<dim3(8, 32), 256, 0, stream>>>(Obf, owtbf, out_bias, out);
}

// Round 3
// 350.841 us; speedup vs baseline: 3.0121x; 1.8152x over previous
//
#include <hip/hip_runtime.h>
#include <cstdint>

// Problem constants: L=S=1024, N=4, E=1024, H=16, D=64
typedef __bf16 bf16x8 __attribute__((ext_vector_type(8)));
typedef float f32x4 __attribute__((ext_vector_type(4)));

// ws layout (float-unit offsets):
static const size_t OFF_QW2BF = 0;         // [k*64+i][j] bf16 (1M ushort)
static const size_t OFF_KWBF  = 524288;    // [o][j] bf16
static const size_t OFF_VWBF  = 1048576;   // [o][j] bf16
static const size_t OFF_OWTBF = 1572864;   // [o][j] bf16 (out_w^T)
static const size_t OFF_QB2   = 2097152;   // 1024 f32
static const size_t OFF_QWBF  = 2098176;   // [n][k][l][i] bf16 (4M ushort)
static const size_t OFF_KHBF  = 4195328;   // [n][k][s][i] bf16
static const size_t OFF_VTBF  = 6292480;   // [n][k][i][s] bf16 (V^T per head)
static const size_t OFF_ST    = 8389632;   // [n][k][l][{m,Z}] f32 131072
static const size_t OFF_OBF   = 8520704;   // [l*4+n][e] bf16 (4M ushort)

__device__ inline unsigned short f2bf(float f) {
  union { float f; unsigned u; } v; v.f = f;
  const unsigned r = v.u + 0x7FFFu + ((v.u >> 16) & 1u);   // RNE
  return (unsigned short)(r >> 16);
}

// ---------------------------------------------------------------------------
// K0: fold attn_W into q_w (bf16 out): qw2[(k,i),j] = sum_o q_w[o*16+k,j]*attn_W[o,i,k]/32
__global__ __launch_bounds__(256) void k_qw2(const float* __restrict__ qw,
    const float* __restrict__ attnW, const float* __restrict__ bias0,
    unsigned short* __restrict__ qw2, float* __restrict__ qb2) {
  const int b = blockIdx.x;          // = k*64 + i
  const int k = b >> 6, i = b & 63;
  const int tid = threadIdx.x;
  __shared__ float aw[64];
  if (tid < 64) aw[tid] = attnW[(tid * 64 + i) * 16 + k] * 0.03125f; // fold 1/sqrt(E)
  __syncthreads();
  for (int j = tid; j < 1024; j += 256) {
    float acc = 0.f;
#pragma unroll 8
    for (int o = 0; o < 64; ++o) acc = fmaf(qw[(o * 16 + k) * 1024 + j], aw[o], acc);
    qw2[(size_t)b * 1024 + j] = f2bf(acc);
  }
  if (tid == 0) {
    float acc = 0.f;
    for (int o = 0; o < 64; ++o) acc = fmaf(bias0[o * 16 + k], aw[o], acc);
    qb2[b] = acc;
  }
}

// ---------------------------------------------------------------------------
// Convert k_w and v_w to bf16 (row layout preserved: [o][j])
__global__ __launch_bounds__(256) void k_cvt2(const float* __restrict__ a,
    const float* __restrict__ b, unsigned short* __restrict__ oa,
    unsigned short* __restrict__ ob) {
  const int i = blockIdx.x * 256 + threadIdx.x;
  const float4 va = ((const float4*)a)[i];
  ushort4 ha; ha.x = f2bf(va.x); ha.y = f2bf(va.y); ha.z = f2bf(va.z); ha.w = f2bf(va.w);
  ((ushort4*)oa)[i] = ha;
  const float4 vb = ((const float4*)b)[i];
  ushort4 hb; hb.x = f2bf(vb.x); hb.y = f2bf(vb.y); hb.z = f2bf(vb.z); hb.w = f2bf(vb.w);
  ((ushort4*)ob)[i] = hb;
}

// ---------------------------------------------------------------------------
// Transpose out_w [j][o] -> owT [o][j] bf16
__global__ __launch_bounds__(256) void k_tr(const float* __restrict__ w,
    unsigned short* __restrict__ wt) {
  __shared__ float t[64][65];
  const int j0 = blockIdx.y * 64, o0 = blockIdx.x * 64;
  const int tid = threadIdx.x;
  const int r = tid >> 4, c4 = tid & 15;
#pragma unroll
  for (int q = 0; q < 4; ++q) {
    const int row = r + q * 16;
    const float4 v = *(const float4*)&w[(size_t)(j0 + row) * 1024 + o0 + c4 * 4];
    t[row][c4 * 4 + 0] = v.x; t[row][c4 * 4 + 1] = v.y;
    t[row][c4 * 4 + 2] = v.z; t[row][c4 * 4 + 3] = v.w;
  }
  __syncthreads();
#pragma unroll
  for (int q = 0; q < 4; ++q) {
    const int orow = r + q * 16;
    ushort4 h;
    h.x = f2bf(t[c4 * 4 + 0][orow]); h.y = f2bf(t[c4 * 4 + 1][orow]);
    h.z = f2bf(t[c4 * 4 + 2][orow]); h.w = f2bf(t[c4 * 4 + 3][orow]);
    *(ushort4*)&wt[(size_t)(o0 + orow) * 1024 + j0 + c4 * 4] = h;
  }
}

// ---------------------------------------------------------------------------
// bf16 MFMA GEMM: C[m,o] = sum_j A[m,j]*B[o,j] + bias[o].  M=4096,O=1024,K=1024.
// MODE 0: A fp32 (Q), epilogue bf16 scatter -> Qw[n][k][l][i] (o = k*64+i)
// MODE 1: A fp32 (K), epilogue bf16 scatter -> Kh[n][k][s][i] (o = i*16+k)
// MODE 3: A fp32 (V), epilogue bf16 scatter -> Vt[n][k][i][s] (o = i*16+k)
// MODE 2: A bf16 (Obf), epilogue f32 direct C[m*1024+o]
template <int MODE>
__global__ __launch_bounds__(256) void k_gemm(const void* __restrict__ Ap,
    const unsigned short* __restrict__ Bbf, const float* __restrict__ bias,
    void* __restrict__ C) {
  __shared__ unsigned short As[128][40];
  __shared__ unsigned short Bs[128][40];
  const int tid = threadIdx.x;
  const int wid = tid >> 6, lane = tid & 63;
  const int wr = wid >> 1, wc = wid & 1;
  const int lr = lane & 15, lk = lane >> 4;
  const int m0 = blockIdx.y * 128, o0 = blockIdx.x * 128;
  f32x4 acc[4][4];
#pragma unroll
  for (int i = 0; i < 4; ++i)
#pragma unroll
    for (int j = 0; j < 4; ++j) acc[i][j] = (f32x4){0.f, 0.f, 0.f, 0.f};

  for (int k0 = 0; k0 < 1024; k0 += 32) {
    if (MODE == 2) {
      const unsigned short* A = (const unsigned short*)Ap;
#pragma unroll
      for (int q = 0; q < 2; ++q) {
        const int idx = tid + q * 256;
        const int row = idx >> 2, c8 = idx & 3;
        *(int4*)&As[row][c8 * 8] =
            *(const int4*)&A[(size_t)(m0 + row) * 1024 + k0 + c8 * 8];
      }
    } else {
      const float* A = (const float*)Ap;
#pragma unroll
      for (int q = 0; q < 4; ++q) {
        const int idx = tid + q * 256;
        const int row = idx >> 3, c4 = idx & 7;
        const float4 v = *(const float4*)&A[(size_t)(m0 + row) * 1024 + k0 + c4 * 4];
        ushort4 h; h.x = f2bf(v.x); h.y = f2bf(v.y); h.z = f2bf(v.z); h.w = f2bf(v.w);
        *(ushort4*)&As[row][c4 * 4] = h;
      }
    }
#pragma unroll
    for (int q = 0; q < 2; ++q) {
      const int idx = tid + q * 256;
      const int row = idx >> 2, c8 = idx & 3;
      *(int4*)&Bs[row][c8 * 8] =
          *(const int4*)&Bbf[(size_t)(o0 + row) * 1024 + k0 + c8 * 8];
    }
    __syncthreads();
    bf16x8 af[4], bfr[4];
#pragma unroll
    for (int f = 0; f < 4; ++f)
      af[f] = *(const bf16x8*)&As[wr * 64 + f * 16 + lr][lk * 8];
#pragma unroll
    for (int f = 0; f < 4; ++f)
      bfr[f] = *(const bf16x8*)&Bs[wc * 64 + f * 16 + lr][lk * 8];
#pragma unroll
    for (int i = 0; i < 4; ++i)
#pragma unroll
      for (int j = 0; j < 4; ++j)
        acc[i][j] = __builtin_amdgcn_mfma_f32_16x16x32_bf16(af[i], bfr[j], acc[i][j], 0, 0, 0);
    __syncthreads();
  }
#pragma unroll
  for (int fi = 0; fi < 4; ++fi)
#pragma unroll
    for (int fj = 0; fj < 4; ++fj) {
      const int o = o0 + wc * 64 + fj * 16 + lr;
      const float bo = bias[o];
#pragma unroll
      for (int t = 0; t < 4; ++t) {
        const int m = m0 + wr * 64 + fi * 16 + lk * 4 + t;
        const float v = acc[fi][fj][t] + bo;
        if (MODE == 0) {
          const int kk = o >> 6, ii = o & 63, l = m >> 2, nn = m & 3;
          ((unsigned short*)C)[(((size_t)(nn * 16 + kk) * 1024 + l) << 6) + ii] = f2bf(v);
        } else if (MODE == 1) {
          const int kk = o & 15, ii = o >> 4, s = m >> 2, nn = m & 3;
          ((unsigned short*)C)[(((size_t)(nn * 16 + kk) * 1024 + s) << 6) + ii] = f2bf(v);
        } else if (MODE == 3) {
          const int kk = o & 15, ii = o >> 4, s = m >> 2, nn = m & 3;
          ((unsigned short*)C)[(((size_t)(nn * 16 + kk) * 64 + ii) << 10) + s] = f2bf(v);
        } else {
          ((float*)C)[(size_t)m * 1024 + o] = v;
        }
      }
    }
}

// ---------------------------------------------------------------------------
// MFMA flash: per (n,k,l-tile=64). 4 waves x 16 q-rows. Q frags in regs;
// K [s][i] and Vt [i][s] in XOR-swizzled LDS (pre-swizzled global source,
// linear LDS write, swizzled b128 frag reads). P via wave-private LDS tile.
// T14: next tile's global loads issued before compute. Writes stats + Obf.
__global__ __launch_bounds__(256) void k_flash(
    const unsigned short* __restrict__ Qbf, const unsigned short* __restrict__ Khbf,
    const unsigned short* __restrict__ Vtbf, float* __restrict__ stats,
    unsigned short* __restrict__ Obf) {
  __shared__ unsigned short Ks[64 * 64];
  __shared__ unsigned short Vs[64 * 64];
  __shared__ unsigned short Ps[64 * 64];
  const int ob = blockIdx.x;
  const int b = (ob & 7) * 128 + (ob >> 3);   // bijective XCD swizzle (1024%8==0)
  const int lt = b & 15, k = (b >> 4) & 15, n = b >> 8;
  const int l0 = lt * 64;
  const int tid = threadIdx.x, w = tid >> 6, lane = tid & 63;
  const int lr = lane & 15, lk = lane >> 4;
  const size_t hb = (size_t)(n * 16 + k) * 65536;
  // Q fragments (A: row = lr, k-chunk = lk*8 / 32+lk*8)
  const unsigned short* qrow = Qbf + hb + (size_t)(l0 + w * 16 + lr) * 64;
  const bf16x8 qa0 = *(const bf16x8*)(qrow + lk * 8);
  const bf16x8 qa1 = *(const bf16x8*)(qrow + 32 + lk * 8);
  // staging: part q covers LDS 16B-chunk idx=q*256+tid (linear); source chunk
  // pre-swizzled: c = pos ^ (row&7)
  int srow[2], scol[2];
#pragma unroll
  for (int q = 0; q < 2; ++q) {
    const int idx = q * 256 + tid;
    srow[q] = idx >> 3;
    scol[q] = (((idx & 7) ^ ((idx >> 3) & 7)) << 3);
  }
  int4 kreg[2], vreg[2];
#pragma unroll
  for (int q = 0; q < 2; ++q) {
    kreg[q] = *(const int4*)(Khbf + hb + (size_t)srow[q] * 64 + scol[q]);
    vreg[q] = *(const int4*)(Vtbf + hb + (size_t)srow[q] * 1024 + scol[q]);
  }
#pragma unroll
  for (int q = 0; q < 2; ++q) {
    *(int4*)&Ks[(q * 256 + tid) * 8] = kreg[q];
    *(int4*)&Vs[(q * 256 + tid) * 8] = vreg[q];
  }
  __syncthreads();

  float m_r[4], Zr[4];
  f32x4 oacc[4];
#pragma unroll
  for (int t = 0; t < 4; ++t) { m_r[t] = -1e30f; Zr[t] = 0.f; }
#pragma unroll
  for (int it = 0; it < 4; ++it) oacc[it] = (f32x4){0.f, 0.f, 0.f, 0.f};

  for (int s0 = 0; s0 < 1024; s0 += 64) {
    if (s0 < 960) {   // T14: issue next-tile loads early
#pragma unroll
      for (int q = 0; q < 2; ++q) {
        kreg[q] = *(const int4*)(Khbf + hb + (size_t)(s0 + 64 + srow[q]) * 64 + scol[q]);
        vreg[q] = *(const int4*)(Vtbf + hb + (size_t)srow[q] * 1024 + s0 + 64 + scol[q]);
      }
    }
    // QK^T: S[q][s], q-rows = lk*4+t, s-cols = st*16+lr
    f32x4 sc[4];
#pragma unroll
    for (int st = 0; st < 4; ++st) {
      const int r = st * 16 + lr;
      const bf16x8 kb0 = *(const bf16x8*)&Ks[r * 64 + ((lk ^ (r & 7)) << 3)];
      const bf16x8 kb1 = *(const bf16x8*)&Ks[r * 64 + (((4 + lk) ^ (r & 7)) << 3)];
      f32x4 z = (f32x4){0.f, 0.f, 0.f, 0.f};
      z = __builtin_amdgcn_mfma_f32_16x16x32_bf16(qa0, kb0, z, 0, 0, 0);
      sc[st] = __builtin_amdgcn_mfma_f32_16x16x32_bf16(qa1, kb1, z, 0, 0, 0);
    }
    // online softmax (row reduce across lr lanes via shfl_xor)
    float fac[4];
#pragma unroll
    for (int t = 0; t < 4; ++t) {
      float v = fmaxf(fmaxf(sc[0][t], sc[1][t]), fmaxf(sc[2][t], sc[3][t]));
      v = fmaxf(v, __shfl_xor(v, 1));
      v = fmaxf(v, __shfl_xor(v, 2));
      v = fmaxf(v, __shfl_xor(v, 4));
      v = fmaxf(v, __shfl_xor(v, 8));
      const float mn = fmaxf(m_r[t], v);
      fac[t] = __expf(m_r[t] - mn);
      m_r[t] = mn;
    }
    float rs[4] = {0.f, 0.f, 0.f, 0.f};
    const int prow_b = w * 16 + lk * 4;
#pragma unroll
    for (int st = 0; st < 4; ++st) {
      const int s = st * 16 + lr;
#pragma unroll
      for (int t = 0; t < 4; ++t) {
        const float p = __expf(sc[st][t] - m_r[t]);
        rs[t] += p;
        const int row = prow_b + t;
        Ps[row * 64 + (((s >> 3) ^ (row & 7)) << 3) + (s & 7)] = f2bf(p);
      }
    }
#pragma unroll
    for (int t = 0; t < 4; ++t) {
      float v = rs[t];
      v += __shfl_xor(v, 1); v += __shfl_xor(v, 2);
      v += __shfl_xor(v, 4); v += __shfl_xor(v, 8);
      Zr[t] = Zr[t] * fac[t] + v;
    }
    const f32x4 facv = {fac[0], fac[1], fac[2], fac[3]};
    // PV: O[q][i] += P[q][s] * Vt[i][s]  (P wave-private in LDS, no barrier)
    const int pr_ = w * 16 + lr;
    const bf16x8 pa0 = *(const bf16x8*)&Ps[pr_ * 64 + ((lk ^ (pr_ & 7)) << 3)];
    const bf16x8 pa1 = *(const bf16x8*)&Ps[pr_ * 64 + (((4 + lk) ^ (pr_ & 7)) << 3)];
#pragma unroll
    for (int it = 0; it < 4; ++it) {
      const int r = it * 16 + lr;
      const bf16x8 bv0 = *(const bf16x8*)&Vs[r * 64 + ((lk ^ (r & 7)) << 3)];
      const bf16x8 bv1 = *(const bf16x8*)&Vs[r * 64 + (((4 + lk) ^ (r & 7)) << 3)];
      f32x4 o = oacc[it] * facv;
      o = __builtin_amdgcn_mfma_f32_16x16x32_bf16(pa0, bv0, o, 0, 0, 0);
      oacc[it] = __builtin_amdgcn_mfma_f32_16x16x32_bf16(pa1, bv1, o, 0, 0, 0);
    }
    __syncthreads();                      // all K/V reads done
    if (s0 < 960) {
#pragma unroll
      for (int q = 0; q < 2; ++q) {
        *(int4*)&Ks[(q * 256 + tid) * 8] = kreg[q];
        *(int4*)&Vs[(q * 256 + tid) * 8] = vreg[q];
      }
    }
    __syncthreads();                      // staged
  }

  float izr[4];
#pragma unroll
  for (int t = 0; t < 4; ++t) izr[t] = 1.f / Zr[t];
  if (lr == 0) {
#pragma unroll
    for (int t = 0; t < 4; ++t) {
      const size_t so = ((size_t)(n * 16 + k) * 1024 + l0 + w * 16 + lk * 4 + t) * 2;
      stats[so] = m_r[t];
      stats[so + 1] = Zr[t];
    }
  }
#pragma unroll
  for (int it = 0; it < 4; ++it)
#pragma unroll
    for (int t = 0; t < 4; ++t) {
      const int l = l0 + w * 16 + lk * 4 + t;
      const int i = it * 16 + lr;
      Obf[(size_t)(l * 4 + n) * 1024 + i * 16 + k] = f2bf(oacc[it][t] * izr[t]);
    }
}

// ---------------------------------------------------------------------------
// Wmap pass (MFMA): per (n, l-tile=64, s-tile=64): recompute scores for 16
// heads from bf16 Qw/Kh, normalize with stored stats, sum -> Wmap[l][s][n]/H.
__global__ __launch_bounds__(256) void k_wmap(const unsigned short* __restrict__ Qbf,
    const unsigned short* __restrict__ Khbf, const float* __restrict__ stats,
    float* __restrict__ Wmap) {
  __shared__ unsigned short Qs[64 * 64];
  __shared__ unsigned short Ksh[64 * 64];
  const int ob = blockIdx.x;
  const int b = (ob & 7) * 128 + (ob >> 3);
  const int st = b & 15, lt = (b >> 4) & 15, n = b >> 8;
  const int l0 = lt * 64, s0 = st * 64;
  const int tid = threadIdx.x, w = tid >> 6, lane = tid & 63;
  const int lr = lane & 15, lk = lane >> 4;
  int srow[2], scol[2];
#pragma unroll
  for (int q = 0; q < 2; ++q) {
    const int idx = q * 256 + tid;
    srow[q] = idx >> 3;
    scol[q] = (((idx & 7) ^ ((idx >> 3) & 7)) << 3);
  }
  int4 qreg[2], kreg[2];
  {
    const size_t hb = (size_t)(n * 16) * 65536;
#pragma unroll
    for (int q = 0; q < 2; ++q) {
      qreg[q] = *(const int4*)(Qbf + hb + (size_t)(l0 + srow[q]) * 64 + scol[q]);
      kreg[q] = *(const int4*)(Khbf + hb + (size_t)(s0 + srow[q]) * 64 + scol[q]);
    }
  }
#pragma unroll
  for (int q = 0; q < 2; ++q) {
    *(int4*)&Qs[(q * 256 + tid) * 8] = qreg[q];
    *(int4*)&Ksh[(q * 256 + tid) * 8] = kreg[q];
  }
  __syncthreads();

  f32x4 wsum[4];
#pragma unroll
  for (int i = 0; i < 4; ++i) wsum[i] = (f32x4){0.f, 0.f, 0.f, 0.f};

  for (int k = 0; k < 16; ++k) {
    if (k < 15) {
      const size_t hb = (size_t)(n * 16 + k + 1) * 65536;
#pragma unroll
      for (int q = 0; q < 2; ++q) {
        qreg[q] = *(const int4*)(Qbf + hb + (size_t)(l0 + srow[q]) * 64 + scol[q]);
        kreg[q] = *(const int4*)(Khbf + hb + (size_t)(s0 + srow[q]) * 64 + scol[q]);
      }
    }
    const int qr = w * 16 + lr;
    const bf16x8 a0 = *(const bf16x8*)&Qs[qr * 64 + ((lk ^ (qr & 7)) << 3)];
    const bf16x8 a1 = *(const bf16x8*)&Qs[qr * 64 + (((4 + lk) ^ (qr & 7)) << 3)];
    float mv[4], izv[4];
#pragma unroll
    for (int t = 0; t < 4; ++t) {
      const float2 mz = *(const float2*)(stats +
          ((size_t)(n * 16 + k) * 1024 + l0 + w * 16 + lk * 4 + t) * 2);
      mv[t] = mz.x; izv[t] = 1.f / mz.y;
    }
#pragma unroll
    for (int st2 = 0; st2 < 4; ++st2) {
      const int r = st2 * 16 + lr;
      const bf16x8 kb0 = *(const bf16x8*)&Ksh[r * 64 + ((lk ^ (r & 7)) << 3)];
      const bf16x8 kb1 = *(const bf16x8*)&Ksh[r * 64 + (((4 + lk) ^ (r & 7)) << 3)];
      f32x4 z = (f32x4){0.f, 0.f, 0.f, 0.f};
      z = __builtin_amdgcn_mfma_f32_16x16x32_bf16(a0, kb0, z, 0, 0, 0);
      z = __builtin_amdgcn_mfma_f32_16x16x32_bf16(a1, kb1, z, 0, 0, 0);
#pragma unroll
      for (int t = 0; t < 4; ++t)
        wsum[st2][t] += __expf(z[t] - mv[t]) * izv[t];
    }
    __syncthreads();
    if (k < 15) {
#pragma unroll
      for (int q = 0; q < 2; ++q) {
        *(int4*)&Qs[(q * 256 + tid) * 8] = qreg[q];
        *(int4*)&Ksh[(q * 256 + tid) * 8] = kreg[q];
      }
    }
    __syncthreads();
  }
#pragma unroll
  for (int st2 = 0; st2 < 4; ++st2)
#pragma unroll
    for (int t = 0; t < 4; ++t) {
      const int l = l0 + w * 16 + lk * 4 + t;
      const int s = s0 + st2 * 16 + lr;
      Wmap[((size_t)l * 1024 + s) * 4 + n] = wsum[st2][t] * 0.0625f;
    }
}

// ---------------------------------------------------------------------------
extern "C" void kernel_launch(void* const* d_in, const int* in_sizes, int n_in,
                              void* d_out, int out_size, void* d_ws, size_t ws_size,
                              hipStream_t stream) {
  (void)in_sizes; (void)n_in; (void)out_size; (void)ws_size;
  const float* Q        = (const float*)d_in[0];
  const float* K        = (const float*)d_in[1];
  const float* V        = (const float*)d_in[2];
  const float* q_w      = (const float*)d_in[3];
  const float* k_w      = (const float*)d_in[4];
  const float* v_w      = (const float*)d_in[5];
  const float* out_w    = (const float*)d_in[6];
  const float* in_bias  = (const float*)d_in[7];
  const float* out_bias = (const float*)d_in[8];
  const float* attn_W   = (const float*)d_in[9];
  float* ws = (float*)d_ws;
  unsigned short* qw2bf = (unsigned short*)(ws + OFF_QW2BF);
  unsigned short* kwbf  = (unsigned short*)(ws + OFF_KWBF);
  unsigned short* vwbf  = (unsigned short*)(ws + OFF_VWBF);
  unsigned short* owtbf = (unsigned short*)(ws + OFF_OWTBF);
  float* qb2 = ws + OFF_QB2;
  unsigned short* Qwbf = (unsigned short*)(ws + OFF_QWBF);
  unsigned short* Khbf = (unsigned short*)(ws + OFF_KHBF);
  unsigned short* Vtbf = (unsigned short*)(ws + OFF_VTBF);
  float* st = ws + OFF_ST;
  unsigned short* Obf = (unsigned short*)(ws + OFF_OBF);
  float* out  = (float*)d_out;
  float* Wmap = out + 4194304;

  k_qw2<<<1024, 256, 0, stream>>>(q_w, attn_W, in_bias, qw2bf, qb2);
  k_cvt2<<<1024, 256, 0, stream>>>(k_w, v_w, kwbf, vwbf);
  k_tr<<<dim3(16, 16), 256, 0, stream>>>(out_w, owtbf);
  k_gemm<0><<<dim3(8, 32), 256, 0, stream>>>(Q, qw2bf, qb2, Qwbf);
  k_gemm<1><<<dim3(8, 32), 256, 0, stream>>>(K, kwbf, in_bias + 1024, Khbf);
  k_gemm<3><<<dim3(8, 32), 256, 0, stream>>>(V, vwbf, in_bias + 2048, Vtbf);
  k_flash<<<1024, 256, 0, stream>>>(Qwbf, Khbf, Vtbf, st, Obf);
  k_wmap<<<1024, 256, 0, stream>>>(Qwbf, Khbf, st, Wmap);
  k_gemm<2><<<dim3(8, 32), 256, 0, stream>>>(Obf, owtbf, out_bias, out);
}